// Round 1
// baseline (9555.617 us; speedup 1.0000x reference)
//
#include <hip/hip_runtime.h>
#include <math.h>

// ---------------------------------------------------------------------------
// Problem constants
// ---------------------------------------------------------------------------
#define ET 64          // edges per block
#define EPW 16         // edges per wave
#define NODE_DIM 240

// path tables: PATHS = [(0,0,0),(1,1,0),(2,2,0),(0,1,1),(1,0,1),(1,2,1),
//                       (2,1,1),(0,2,2),(2,0,2),(1,1,2),(2,2,2)]
// tp_w offsets (floats):
//   0,16384,24576,28672,36864,40960,45056,47104,51200,52224,54272  (total 55296)
// w3j offsets: 0,1,10,35,44,53,98,143,168,193,238 (total 363)

// ---------------------------------------------------------------------------
// Wigner-3j init kernel (exact port of the reference construction)
// ---------------------------------------------------------------------------
struct cplx { double re, im; };
__device__ inline cplx cmul(cplx a, cplx b) {
    return { a.re*b.re - a.im*b.im, a.re*b.im + a.im*b.re };
}

__device__ double dfact(int n) { double r = 1.0; for (int i = 2; i <= n; ++i) r *= i; return r; }

__device__ double su2_cg(int j1, int m1, int j2, int m2, int j3, int m3) {
    if (m3 != m1 + m2) return 0.0;
    int vmin = max(max(-j1 + j2 + m3, -j1 + m1), 0);
    int vmax = min(min(j2 + j3 + m1, j3 - j1 + j2), j3 + m3);
    double C = sqrt((2.0*j3 + 1.0) * dfact(j3 + j1 - j2) * dfact(j3 - j1 + j2) * dfact(j1 + j2 - j3)
                    * dfact(j3 + m3) * dfact(j3 - m3)
                    / (dfact(j1 + j2 + j3 + 1) * dfact(j1 - m1) * dfact(j1 + m1)
                       * dfact(j2 - m2) * dfact(j2 + m2)));
    double S = 0.0;
    for (int v = vmin; v <= vmax; ++v) {
        double sgn = ((v + j2 + m2) & 1) ? -1.0 : 1.0;
        S += sgn * dfact(j2 + j3 + m1 - v) * dfact(j1 - m1 + v)
             / (dfact(v) * dfact(j3 - j1 + j2 - v) * dfact(j3 + m3 - v) * dfact(v + j1 - j2 - m3));
    }
    return C * S;
}

// element (a,b) of (-i)^l * q  where q is the real->complex change of basis
__device__ cplx rtc(int l, int a, int b) {
    double re = 0.0, im = 0.0;
    const double inv_s2 = 0.70710678118654752440;
    int m = a - l;
    if (m < 0) {
        if (b == l - m)      re = inv_s2;        // col l+|m|
        else if (b == l + m) im = -inv_s2;       // col l-|m|
    } else if (m == 0) {
        if (b == l) re = 1.0;
    } else {
        double s = (m & 1) ? -1.0 : 1.0;
        if (b == l + m)      re = s * inv_s2;
        else if (b == l - m) im = s * inv_s2;
    }
    if (l == 1) { double t = re; re = im; im = -t; }     // * (-i)
    else if (l == 2) { re = -re; im = -im; }             // * (-1)
    return { re, im };
}

__global__ void w3j_init(float* __restrict__ out) {
    __shared__ double sRe[363], sIm[363];
    __shared__ double sNorm[11];
    __shared__ int    sUse[11];
    const int L1A[11] = {0,1,2,0,1,1,2,0,2,1,2};
    const int L2A[11] = {0,1,2,1,0,2,1,2,0,1,2};
    const int L3A[11] = {0,0,0,1,1,1,1,2,2,2,2};
    const int OFF[12] = {0,1,10,35,44,53,98,143,168,193,238,363};
    int t = threadIdx.x;
    if (t < 363) {
        int p = 0;
        while (p < 10 && t >= OFF[p+1]) ++p;
        int rel = t - OFF[p];
        int a1 = L1A[p], a2 = L2A[p], a3 = L3A[p];
        int n1 = 2*a1 + 1, n2 = 2*a2 + 1, n3 = 2*a3 + 1;
        int jj = rel / (n2*n3), ll = (rel / n3) % n2, mm = rel % n3;
        double cr = 0.0, ci = 0.0;
        for (int i = 0; i < n1; ++i)
            for (int k = 0; k < n2; ++k)
                for (int n = 0; n < n3; ++n) {
                    double c = su2_cg(a1, i - a1, a2, k - a2, a3, n - a3);
                    if (c == 0.0) continue;
                    cplx q1 = rtc(a1, i, jj);
                    cplx q2 = rtc(a2, k, ll);
                    cplx q3 = rtc(a3, n, mm); q3.im = -q3.im;   // conj
                    cplx pr = cmul(cmul(q1, q2), q3);
                    cr += pr.re * c; ci += pr.im * c;
                }
        sRe[t] = cr; sIm[t] = ci;
    }
    __syncthreads();
    if (t < 11) {
        double nr = 0.0, ni = 0.0;
        for (int e = OFF[t]; e < OFF[t+1]; ++e) { nr += sRe[e]*sRe[e]; ni += sIm[e]*sIm[e]; }
        int use_im = (sqrt(nr) < 1e-8) ? 1 : 0;
        sUse[t] = use_im;
        sNorm[t] = sqrt(use_im ? ni : nr);
    }
    __syncthreads();
    if (t < 363) {
        int p = 0;
        while (p < 10 && t >= OFF[p+1]) ++p;
        out[t] = (float)((sUse[p] ? sIm[t] : sRe[t]) / sNorm[p]);
    }
}

// ---------------------------------------------------------------------------
// Main kernel
// ---------------------------------------------------------------------------
// one path, templated so all small arrays stay in registers
template<int l1, int l2, int l3>
__device__ void do_path(int tid, int woff, int cgoff,
                        const float* __restrict__ node_feat,
                        const float* __restrict__ tp_w,
                        const float* __restrict__ w3j,
                        float* sW, float (*sAcc)[96],
                        const float (*sWl)[12], const float (*sY)[8],
                        const int* sSrc)
{
    constexpr int U  = (l1 == 0) ? 64 : (l1 == 1) ? 32 : 16;
    constexpr int WD = (l3 == 0) ? 64 : (l3 == 1) ? 32 : 16;
    constexpr int NI = 2*l1 + 1, NJ = 2*l2 + 1, NK = 2*l3 + 1;
    constexpr int UC = (U*4*WD > 8192) ? (8192 / (4*WD)) : U;   // u-chunk that fits 32KB
    constexpr int NE = 64 / WD;        // lane groups (edges side-by-side in a wave)
    constexpr int P  = EPW / (NE * 2); // passes; 2 edges per lane per pass
    constexpr int NODE_OFF = (l1 == 0) ? 0 : (l1 == 1) ? 64 : 160;

    int wave = tid >> 6, lane = tid & 63;
    int g = lane / WD, w = lane % WD;

    for (int u0 = 0; u0 < U; u0 += UC) {
        __syncthreads();
        // stage W chunk to LDS, transposed to [u][w][v] so reads are b128
        for (int idx = tid; idx < UC*4*WD; idx += 256) {
            int u_rel = idx / (4*WD);
            int rem   = idx - u_rel*(4*WD);
            int v     = rem / WD;
            int ww    = rem - v*WD;
            sW[(u_rel*WD + ww)*4 + v] = tp_w[woff + (u0 + u_rel)*(4*WD) + rem];
        }
        __syncthreads();

        for (int p = 0; p < P; ++p) {
            int elBase = wave*EPW + (p*NE + g)*2;
            float wlv[2][4];
            float cy[2][NI][NK];
            float ak[2][NK];
            const float* nbase[2];
            #pragma unroll
            for (int jj = 0; jj < 2; ++jj) {
                int el = elBase + jj;
                #pragma unroll
                for (int v = 0; v < 4; ++v) wlv[jj][v] = sWl[el][l2*4 + v];
                #pragma unroll
                for (int i = 0; i < NI; ++i)
                    #pragma unroll
                    for (int k = 0; k < NK; ++k) cy[jj][i][k] = 0.0f;
                #pragma unroll
                for (int j = 0; j < NJ; ++j) {
                    float yj = (l2 == 0) ? 1.0f : (l2 == 1 ? sY[el][j] : sY[el][3 + j]);
                    #pragma unroll
                    for (int i = 0; i < NI; ++i)
                        #pragma unroll
                        for (int k = 0; k < NK; ++k)
                            cy[jj][i][k] += w3j[cgoff + (i*NJ + j)*NK + k] * yj;
                }
                #pragma unroll
                for (int k = 0; k < NK; ++k) ak[jj][k] = 0.0f;
                nbase[jj] = node_feat + (long)sSrc[el]*NODE_DIM + NODE_OFF;
            }
            for (int ur = 0; ur < UC; ++ur) {
                int u = u0 + ur;
                float4 wv = *reinterpret_cast<const float4*>(&sW[(ur*WD + w)*4]);
                #pragma unroll
                for (int jj = 0; jj < 2; ++jj) {
                    float a = wv.x*wlv[jj][0] + wv.y*wlv[jj][1] + wv.z*wlv[jj][2] + wv.w*wlv[jj][3];
                    #pragma unroll
                    for (int i = 0; i < NI; ++i) {
                        float an = a * nbase[jj][u*NI + i];
                        #pragma unroll
                        for (int k = 0; k < NK; ++k) ak[jj][k] += an * cy[jj][i][k];
                    }
                }
            }
            #pragma unroll
            for (int jj = 0; jj < 2; ++jj) {
                int el = elBase + jj;
                #pragma unroll
                for (int k = 0; k < NK; ++k) sAcc[el][w*NK + k] += ak[jj][k];
            }
        }
    }
}

__global__ __launch_bounds__(256, 2)
void edge_main(const float* __restrict__ node_feat,
               const int*   __restrict__ edge_src,
               const float* __restrict__ edge_vec,
               const float* __restrict__ maskp,
               const float* __restrict__ mlp_w1, const float* __restrict__ mlp_b1,
               const float* __restrict__ mlp_w2, const float* __restrict__ mlp_b2,
               const float* __restrict__ tp_w,
               const float* __restrict__ w3j,
               float* __restrict__ out)
{
    __shared__ float sW[8192];          // 32KB: W staging (also phase-0 scratch)
    __shared__ float sAcc[ET][96];      // 24KB: per-edge accumulators for current l3
    __shared__ float sWl[ET][12];
    __shared__ float sY[ET][8];
    __shared__ float sR[ET];
    __shared__ float sRb2[ET];
    __shared__ float sMask[ET];
    __shared__ int   sSrc[ET];

    // phase-0 scratch aliases onto sW (used & done before any W staging)
    float (*sRbf)[32] = (float(*)[32])sW;            // 2048 floats
    float (*sH)[32]   = (float(*)[32])(sW + 2048);   // 2048 floats

    int tid = threadIdx.x;
    long eg0 = (long)blockIdx.x * ET;

    // ---- phase 0a: per-edge geometry -------------------------------------
    if (tid < ET) {
        long eg = eg0 + tid;
        float vx = edge_vec[eg*3 + 0], vy = edge_vec[eg*3 + 1], vz = edge_vec[eg*3 + 2];
        float rn = sqrtf(vx*vx + vy*vy + vz*vz);
        float r  = fmaxf(rn, 1e-12f);
        float inv = 1.0f / r;
        float x = vx*inv, y = vy*inv, z = vz*inv;
        sR[tid] = r;
        float rb = 0.5f * (cosf(r * 3.14159265358979323846f / 5.0f) + 1.0f);
        sRb2[tid] = (r < 5.0f) ? rb*rb : 0.0f;
        sMask[tid] = maskp[eg];
        sSrc[tid]  = edge_src[eg];
        const float s3 = sqrtf(3.0f), s5 = sqrtf(5.0f), s15 = sqrtf(15.0f);
        sY[tid][0] = s3*x; sY[tid][1] = s3*y; sY[tid][2] = s3*z;
        sY[tid][3] = s15*x*z;
        sY[tid][4] = s15*x*y;
        sY[tid][5] = s5*(y*y - 0.5f*(x*x + z*z));
        sY[tid][6] = s15*y*z;
        sY[tid][7] = 0.5f*s15*(z*z - x*x);
    }
    __syncthreads();

    // ---- phase 0b: radial basis ------------------------------------------
    {
        float em5  = expf(-5.0f);
        float step = (1.0f - em5) / 31.0f;
        float beta = 256.0f / ((1.0f - em5) * (1.0f - em5));
        for (int idx = tid; idx < ET*32; idx += 256) {
            int e = idx >> 5, j = idx & 31;
            float mean = em5 + step * j;
            float d = expf(-sR[e]) - mean;
            sRbf[e][j] = sRb2[e] * expf(-beta * d * d);
        }
    }
    __syncthreads();

    // ---- phase 0c: per-l MLP -> edge weights wl --------------------------
    for (int l = 0; l < 3; ++l) {
        for (int idx = tid; idx < ET*32; idx += 256) {
            int e = idx >> 5, j = idx & 31;
            float zacc = mlp_b1[l*32 + j];
            #pragma unroll 8
            for (int rr = 0; rr < 32; ++rr) zacc += sRbf[e][rr] * mlp_w1[(l*32 + rr)*32 + j];
            sH[e][j] = zacc / (1.0f + expf(-zacc));   // silu
        }
        __syncthreads();
        for (int idx = tid; idx < ET*4; idx += 256) {
            int e = idx >> 2, v = idx & 3;
            float zacc = mlp_b2[l*4 + v];
            #pragma unroll 8
            for (int j = 0; j < 32; ++j) zacc += sH[e][j] * mlp_w2[(l*32 + j)*4 + v];
            sWl[e][l*4 + v] = zacc;
        }
        __syncthreads();
    }

    // ---- l3 = 0 group ----------------------------------------------------
    for (int idx = tid; idx < ET*96; idx += 256) ((float*)sAcc)[idx] = 0.0f;
    do_path<0,0,0>(tid,     0,   0, node_feat, tp_w, w3j, sW, sAcc, sWl, sY, sSrc);
    do_path<1,1,0>(tid, 16384,   1, node_feat, tp_w, w3j, sW, sAcc, sWl, sY, sSrc);
    do_path<2,2,0>(tid, 24576,  10, node_feat, tp_w, w3j, sW, sAcc, sWl, sY, sSrc);
    __syncthreads();
    {
        const float alpha = 1.0f / sqrtf(448.0f);
        for (int idx = tid; idx < ET*64; idx += 256) {
            int e = idx >> 6, c = idx & 63;
            out[(eg0 + e)*NODE_DIM + 0 + c] = sAcc[e][c] * alpha * sMask[e];
        }
    }
    __syncthreads();

    // ---- l3 = 1 group ----------------------------------------------------
    for (int idx = tid; idx < ET*96; idx += 256) ((float*)sAcc)[idx] = 0.0f;
    do_path<0,1,1>(tid, 28672,  35, node_feat, tp_w, w3j, sW, sAcc, sWl, sY, sSrc);
    do_path<1,0,1>(tid, 36864,  44, node_feat, tp_w, w3j, sW, sAcc, sWl, sY, sSrc);
    do_path<1,2,1>(tid, 40960,  53, node_feat, tp_w, w3j, sW, sAcc, sWl, sY, sSrc);
    do_path<2,1,1>(tid, 45056,  98, node_feat, tp_w, w3j, sW, sAcc, sWl, sY, sSrc);
    __syncthreads();
    {
        const float alpha = 1.0f / 24.0f;
        for (int idx = tid; idx < ET*96; idx += 256) {
            int e = idx / 96, c = idx - e*96;
            out[(eg0 + e)*NODE_DIM + 64 + c] = sAcc[e][c] * alpha * sMask[e];
        }
    }
    __syncthreads();

    // ---- l3 = 2 group ----------------------------------------------------
    for (int idx = tid; idx < ET*96; idx += 256) ((float*)sAcc)[idx] = 0.0f;
    do_path<0,2,2>(tid, 47104, 143, node_feat, tp_w, w3j, sW, sAcc, sWl, sY, sSrc);
    do_path<2,0,2>(tid, 51200, 168, node_feat, tp_w, w3j, sW, sAcc, sWl, sY, sSrc);
    do_path<1,1,2>(tid, 52224, 193, node_feat, tp_w, w3j, sW, sAcc, sWl, sY, sSrc);
    do_path<2,2,2>(tid, 54272, 238, node_feat, tp_w, w3j, sW, sAcc, sWl, sY, sSrc);
    __syncthreads();
    {
        const float alpha = 1.0f / sqrtf(512.0f);
        for (int idx = tid; idx < ET*80; idx += 256) {
            int e = idx / 80, c = idx - e*80;
            out[(eg0 + e)*NODE_DIM + 160 + c] = sAcc[e][c] * alpha * sMask[e];
        }
    }
}

// ---------------------------------------------------------------------------
// launch
// ---------------------------------------------------------------------------
extern "C" void kernel_launch(void* const* d_in, const int* in_sizes, int n_in,
                              void* d_out, int out_size, void* d_ws, size_t ws_size,
                              hipStream_t stream)
{
    const float* node_feat = (const float*)d_in[0];
    const int*   edge_idx  = (const int*)  d_in[1];
    const float* edge_vec  = (const float*)d_in[2];
    const float* maskp     = (const float*)d_in[3];
    const float* mlp_w1    = (const float*)d_in[4];
    const float* mlp_b1    = (const float*)d_in[5];
    const float* mlp_w2    = (const float*)d_in[6];
    const float* mlp_b2    = (const float*)d_in[7];
    const float* tp_w      = (const float*)d_in[8];
    float* out = (float*)d_out;
    float* w3j = (float*)d_ws;

    int E = in_sizes[3];                 // = N_EDGES = 800000 (divisible by ET)
    const int* edge_src = edge_idx;      // row 0 of (2, E)

    hipLaunchKernelGGL(w3j_init, dim3(1), dim3(512), 0, stream, w3j);
    hipLaunchKernelGGL(edge_main, dim3(E / ET), dim3(256), 0, stream,
                       node_feat, edge_src, edge_vec, maskp,
                       mlp_w1, mlp_b1, mlp_w2, mlp_b2, tp_w, w3j, out);
}